// Round 10
// baseline (273.223 us; speedup 1.0000x reference)
//
#include <hip/hip_runtime.h>
#include <hip/hip_fp16.h>
#include <math.h>

namespace {
constexpr int IH = 224, IW = 224;
constexpr int H2 = 67, W2 = 67;
constexpr int MH = 56, MW = 56;
constexpr int CI = 3, CM = 21;
constexpr int ND = 6;
constexpr int K = 48;
constexpr int HW = IH * IW;    // 50176
constexpr int HW2 = H2 * W2;   // 4489
constexpr float EPS = 1e-8f;
__device__ __constant__ int DILS_C[ND] = {1, 2, 4, 8, 12, 24};
}

struct PosArr { float v[K]; };

__device__ __forceinline__ float wsum64(float v) {
    #pragma unroll
    for (int off = 1; off < 64; off <<= 1) v += __shfl_xor(v, off);
    return v;
}

// ---------------- bilinear downsample imgs 224->67 (align_corners) ----------
__global__ void k_img_down(const float* __restrict__ img, float* __restrict__ img2) {
    int t = blockIdx.x * blockDim.x + threadIdx.x;
    if (t >= CI * HW2) return;
    int c = t / HW2, r = t % HW2;
    int y = r / W2, x = r % W2;
    float fy = (float)y * ((float)(IH - 1) / (float)(H2 - 1));
    float fx = (float)x * ((float)(IW - 1) / (float)(W2 - 1));
    int y0 = (int)floorf(fy); int y1 = min(y0 + 1, IH - 1); float wy = fy - (float)y0;
    int x0 = (int)floorf(fx); int x1 = min(x0 + 1, IW - 1); float wx = fx - (float)x0;
    const float* p = img + c * HW;
    float v00 = p[y0 * IW + x0], v01 = p[y0 * IW + x1];
    float v10 = p[y1 * IW + x0], v11 = p[y1 * IW + x1];
    float r0 = v00 * (1.f - wy) + v10 * wy;
    float r1 = v01 * (1.f - wy) + v11 * wy;
    img2[t] = r0 * (1.f - wx) + r1 * wx;
}

// ---------------- low-res affinity: one WAVE per pixel ----------------------
__global__ void k_aff2(const float* __restrict__ img2, float* __restrict__ aff2) {
    int gtid = blockIdx.x * blockDim.x + threadIdx.x;
    int wave = gtid >> 6;
    int lane = threadIdx.x & 63;
    if (wave >= HW2) return;
    int t = wave;
    int y = t / W2, x = t % W2;

    int k = (lane < K) ? lane : (K - 1);
    int di = k >> 3, o = k & 7;
    int d = DILS_C[di];
    int ym = max(y - d, 0), yp = min(y + d, H2 - 1);
    int xm = max(x - d, 0), xp = min(x + d, W2 - 1);
    int ki = (0x22211000u >> (o * 4)) & 3;
    int kj = (0x21020210u >> (o * 4)) & 3;
    int ry = ki == 0 ? ym : (ki == 1 ? y : yp);
    int rx = kj == 0 ? xm : (kj == 1 ? x : xp);
    int nidx = ry * W2 + rx;

    float av = 0.f;
    #pragma unroll
    for (int c = 0; c < CI; ++c) {
        const float* p = img2 + c * HW2;
        float center = p[y * W2 + x];
        float v = p[nidx];
        float vv = (lane < K) ? v : 0.f;
        float s = wsum64(vv);
        float s2 = wsum64(vv * vv);
        float mean = s * (1.f / (float)K);
        float ss = s2 - (float)K * mean * mean;
        float stdv = sqrtf(fmaxf(ss, 0.f) * (1.f / (float)(K - 1)));
        float inv = 1.f / (stdv + EPS);
        float tt = fabsf(v - center) * inv;
        av += tt * tt;
    }
    if (lane < K) aff2[(size_t)t * K + k] = av;
}

// ---------------- full-res aff + upsampled aff2 + pos -> aff_total ----------
// 16 lanes per pixel; writes afft[t*K + k] as FP16
__global__ void k_aff_total(const float* __restrict__ img,
                            const float* __restrict__ aff2,
                            __half* __restrict__ afft, PosArr pos) {
    int gid = blockIdx.x * blockDim.x + threadIdx.x;
    int t = gid >> 4;
    int lane = threadIdx.x & 15;
    if (t >= HW) return;
    int y = t / IW, x = t % IW;

    int nidx[3];
    int kk[3];
    #pragma unroll
    for (int s = 0; s < 3; ++s) {
        int k = lane + 16 * s;
        kk[s] = k;
        int di = k >> 3, o = k & 7;
        int d = DILS_C[di];
        int ki = (0x22211000u >> (o * 4)) & 3;
        int kj = (0x21020210u >> (o * 4)) & 3;
        int ym = max(y - d, 0), yp = min(y + d, IH - 1);
        int xm = max(x - d, 0), xp = min(x + d, IW - 1);
        int ry = ki == 0 ? ym : (ki == 1 ? y : yp);
        int rx = kj == 0 ? xm : (kj == 1 ? x : xp);
        nidx[s] = ry * IW + rx;
    }

    float av0 = 0.f, av1 = 0.f, av2 = 0.f;
    #pragma unroll
    for (int c = 0; c < CI; ++c) {
        const float* p = img + c * HW;
        float center = p[y * IW + x];
        float n0 = p[nidx[0]], n1 = p[nidx[1]], n2 = p[nidx[2]];
        float s1 = n0 + n1 + n2;
        float s2 = n0 * n0 + n1 * n1 + n2 * n2;
        #pragma unroll
        for (int off = 1; off < 16; off <<= 1) {
            s1 += __shfl_xor(s1, off, 16);
            s2 += __shfl_xor(s2, off, 16);
        }
        float mean = s1 * (1.f / (float)K);
        float ss = s2 - (float)K * mean * mean;
        float inv = 1.f / (sqrtf(fmaxf(ss, 0.f) * (1.f / (float)(K - 1))) + EPS);
        float t0 = fabsf(n0 - center) * inv; av0 += t0 * t0;
        float t1 = fabsf(n1 - center) * inv; av1 += t1 * t1;
        float t2 = fabsf(n2 - center) * inv; av2 += t2 * t2;
    }
    const float sc = -(1.f / (float)CI) / (0.3f * 0.3f);
    av0 *= sc; av1 *= sc; av2 *= sc;
    float m1 = fmaxf(av0, fmaxf(av1, av2));
    #pragma unroll
    for (int off = 1; off < 16; off <<= 1) m1 = fmaxf(m1, __shfl_xor(m1, off, 16));
    float e0 = expf(av0 - m1), e1 = expf(av1 - m1), e2 = expf(av2 - m1);
    float es = e0 + e1 + e2;
    #pragma unroll
    for (int off = 1; off < 16; off <<= 1) es += __shfl_xor(es, off, 16);
    float r1 = 1.f / es;

    float fy = (float)y * ((float)(H2 - 1) / (float)(IH - 1));
    float fx = (float)x * ((float)(W2 - 1) / (float)(IW - 1));
    int y0 = (int)floorf(fy); int y1 = min(y0 + 1, H2 - 1); float wy = fy - (float)y0;
    int x0 = (int)floorf(fx); int x1 = min(x0 + 1, W2 - 1); float wx = fx - (float)x0;
    const float* q00 = aff2 + (size_t)(y0 * W2 + x0) * K;
    const float* q01 = aff2 + (size_t)(y0 * W2 + x1) * K;
    const float* q10 = aff2 + (size_t)(y1 * W2 + x0) * K;
    const float* q11 = aff2 + (size_t)(y1 * W2 + x1) * K;
    float w00 = (1.f - wy) * (1.f - wx), w01 = (1.f - wy) * wx;
    float w10 = wy * (1.f - wx), w11 = wy * wx;
    const float sc2 = -(1.f / (float)CI);
    float b0 = (q00[kk[0]] * w00 + q01[kk[0]] * w01 + q10[kk[0]] * w10 + q11[kk[0]] * w11) * sc2;
    float b1 = (q00[kk[1]] * w00 + q01[kk[1]] * w01 + q10[kk[1]] * w10 + q11[kk[1]] * w11) * sc2;
    float b2 = (q00[kk[2]] * w00 + q01[kk[2]] * w01 + q10[kk[2]] * w10 + q11[kk[2]] * w11) * sc2;
    float m2 = fmaxf(b0, fmaxf(b1, b2));
    #pragma unroll
    for (int off = 1; off < 16; off <<= 1) m2 = fmaxf(m2, __shfl_xor(m2, off, 16));
    float f0 = expf(b0 - m2), f1 = expf(b1 - m2), f2 = expf(b2 - m2);
    float fs = f0 + f1 + f2;
    #pragma unroll
    for (int off = 1; off < 16; off <<= 1) fs += __shfl_xor(fs, off, 16);
    float r2 = 1.f / fs;

    __half* o = afft + (size_t)t * K;
    o[kk[0]] = __float2half(e0 * r1 + f0 * r2 + pos.v[kk[0]]);
    o[kk[1]] = __float2half(e1 * r1 + f1 * r2 + pos.v[kk[1]]);
    o[kk[2]] = __float2half(e2 * r1 + f2 * r2 + pos.v[kk[2]]);
}

// ---------------- mask upsample 56 -> 224 -----------------------------------
__global__ void k_mask_up(const float* __restrict__ m, float* __restrict__ mu) {
    int t = blockIdx.x * blockDim.x + threadIdx.x;
    if (t >= CM * HW) return;
    int c = t / HW, r = t % HW;
    int y = r / IW, x = r % IW;
    float fy = (float)y * ((float)(MH - 1) / (float)(IH - 1));
    float fx = (float)x * ((float)(MW - 1) / (float)(IW - 1));
    int y0 = (int)floorf(fy); int y1 = min(y0 + 1, MH - 1); float wy = fy - (float)y0;
    int x0 = (int)floorf(fx); int x1 = min(x0 + 1, MW - 1); float wx = fx - (float)x0;
    const float* p = m + c * MH * MW;
    float v00 = p[y0 * MW + x0], v01 = p[y0 * MW + x1];
    float v10 = p[y1 * MW + x0], v11 = p[y1 * MW + x1];
    float r0 = v00 * (1.f - wy) + v10 * wy;
    float r1 = v01 * (1.f - wy) + v11 * wy;
    mu[t] = r0 * (1.f - wx) + r1 * wx;
}

// ---------------- one propagation iteration ---------------------------------
// Block = (row y, channel c). LDS = 13 rows x 272 (24-px edge-splat halo;
// 14.1 KB). Staging: interior = R7's uniform 13x56 float4 loop (dwords
// 24..247); halo = separate single uniform pass (no per-wave divergence —
// R9's regression cause). Compute: 112 threads x 2 px, neighbor pairs read
// as float2 (8B-aligned for even d; d=1 scalar+CSE): 52 LDS instr / 128 px
// vs 96. Weights (fp16) rolling-prefetched, 2 px share the addressing.
__global__ __launch_bounds__(256) void k_prop(const float* __restrict__ min_,
                                              const __half* __restrict__ afft,
                                              float* __restrict__ mout) {
    __shared__ float L[13 * 272];   // 14144 B
    int tid = threadIdx.x;
    int bid = blockIdx.x;
    int sw = (bid & 7) * 588 + (bid >> 3);   // 4704 = 8 * 588, bijective
    int y = sw / 21;
    int c = sw - y * 21;

    // weight pointers for this thread's pixel pair (threads 0..111 compute)
    int j0 = 2 * min(tid, 111);
    int t0 = y * IW + j0;
    const uint4* aw0 = (const uint4*)(afft + (size_t)t0 * K);        // px0: 6 uint4
    const uint4* aw1 = (const uint4*)(afft + (size_t)(t0 + 1) * K);  // px1: 6 uint4
    uint4 wa, wb;
    if (tid < 112) { wa = aw0[0]; wb = aw1[0]; }   // di=0 prefetch (hides under staging)

    const int ROW_DY[13] = {-24, -12, -8, -4, -2, -1, 0, 1, 2, 4, 8, 12, 24};
    const float* mc = min_ + (size_t)c * HW;

    // interior staging: uniform, coalesced (dwords 24..247 of each row)
    for (int i = tid; i < 13 * 56; i += 256) {
        int r = i / 56;
        int q = i - r * 56;
        int gy = min(max(y + ROW_DY[r], 0), IH - 1);
        *(float4*)(L + r * 272 + 24 + q * 4) = ((const float4*)(mc + gy * IW))[q];
    }
    // halo staging: one uniform pass, 13 rows x 12 float4 splat slots
    if (tid < 156) {
        int r = tid / 12;
        int s = tid - r * 12;
        int gy = min(max(y + ROW_DY[r], 0), IH - 1);
        const float* row = mc + gy * IW;
        float e = (s < 6) ? row[0] : row[IW - 1];
        int off = r * 272 + ((s < 6) ? s * 4 : 248 + (s - 6) * 4);
        *(float4*)(L + off) = make_float4(e, e, e, e);
    }
    __syncthreads();

    if (tid >= 112) return;

    const int DILS[ND] = {1, 2, 4, 8, 12, 24};
    const int RMI[ND] = {5, 4, 3, 2, 1, 0};
    const int RPI[ND] = {7, 8, 9, 10, 11, 12};
    const float* Bp = L + 24 + j0;      // all offsets from here are >= -1 dword of L
    float acc0 = 0.f, acc1 = 0.f;

    #pragma unroll
    for (int di = 0; di < ND; ++di) {
        uint4 na, nb;
        if (di < 5) { na = aw0[di + 1]; nb = aw1[di + 1]; }   // rolling prefetch
        const float* Lm = Bp + RMI[di] * 272;
        const float* Lc = Bp + 6 * 272;
        const float* Lp = Bp + RPI[di] * 272;
        const __half2* h0 = (const __half2*)&wa;
        const __half2* h1 = (const __half2*)&wb;
        float2 a01 = __half22float2(h0[0]), a23 = __half22float2(h0[1]);
        float2 a45 = __half22float2(h0[2]), a67 = __half22float2(h0[3]);
        float2 b01 = __half22float2(h1[0]), b23 = __half22float2(h1[1]);
        float2 b45 = __half22float2(h1[2]), b67 = __half22float2(h1[3]);
        if (di == 0) {
            // d=1: odd offsets -> scalar reads (shared dwords CSE)
            float m_1 = Lm[-1], m0 = Lm[0], m1 = Lm[1], m2 = Lm[2];
            float c_1 = Lc[-1], c0 = Lc[0], c1 = Lc[1], c2 = Lc[2];
            float p_1 = Lp[-1], p0 = Lp[0], p1 = Lp[1], p2 = Lp[2];
            acc0 += m_1 * a01.x + m0 * a01.y + m1 * a23.x + c_1 * a23.y
                  + c1  * a45.x + p_1 * a45.y + p0 * a67.x + p1 * a67.y;
            acc1 += m0 * b01.x + m1 * b01.y + m2 * b23.x + c0 * b23.y
                  + c2 * b45.x + p0 * b45.y + p1 * b67.x + p2 * b67.y;
        } else {
            const int d = DILS[di];   // even: float2 reads 8B-aligned
            float2 vmm = *(const float2*)(Lm - d);
            float2 vm0 = *(const float2*)(Lm);
            float2 vmp = *(const float2*)(Lm + d);
            float2 vcm = *(const float2*)(Lc - d);
            float2 vcp = *(const float2*)(Lc + d);
            float2 vpm = *(const float2*)(Lp - d);
            float2 vp0 = *(const float2*)(Lp);
            float2 vpp = *(const float2*)(Lp + d);
            acc0 += vmm.x * a01.x + vm0.x * a01.y + vmp.x * a23.x + vcm.x * a23.y
                  + vcp.x * a45.x + vpm.x * a45.y + vp0.x * a67.x + vpp.x * a67.y;
            acc1 += vmm.y * b01.x + vm0.y * b01.y + vmp.y * b23.x + vcm.y * b23.y
                  + vcp.y * b45.x + vpm.y * b45.y + vp0.y * b67.x + vpp.y * b67.y;
        }
        wa = na; wb = nb;
    }
    *(float2*)(mout + (size_t)c * HW + t0) = make_float2(acc0, acc1);
}

extern "C" void kernel_launch(void* const* d_in, const int* in_sizes, int n_in,
                              void* d_out, int out_size, void* d_ws, size_t ws_size,
                              hipStream_t stream) {
    const float* imgs  = (const float*)d_in[0];
    const float* masks = (const float*)d_in[1];
    float* out = (float*)d_out;

    float* ws = (float*)d_ws;
    float* imgs2 = ws;                       // CI*HW2 = 13467 -> pad to 16384
    float* aff2  = imgs2 + 16384;            // HW2*K  = 215472 (layout [HW2][K])
    __half* afft = (__half*)(aff2 + K * HW2);       // HW*K halfs = 4.8 MB
    float* mA    = aff2 + K * HW2 + (K * HW) / 2;   // CM*HW floats
    float* mB    = mA + (size_t)CM * HW;

    // host-side positional softmax (input-independent, same every call)
    PosArr pos;
    {
        double pv[K];
        const int dil[ND] = {1, 2, 4, 8, 12, 24};
        const double s2 = sqrt(2.0);
        for (int di = 0; di < ND; ++di)
            for (int o = 0; o < 8; ++o) {
                double base = (o == 0 || o == 2 || o == 5 || o == 7) ? s2 : 1.0;
                pv[di * 8 + o] = base * (double)dil[di];
            }
        double sum = 0.0; for (int k = 0; k < K; ++k) sum += pv[k];
        double mean = sum / K;
        double ssd = 0.0; for (int k = 0; k < K; ++k) { double d0 = pv[k] - mean; ssd += d0 * d0; }
        double stdv = sqrt(ssd / (K - 1));
        double pa[K];
        double mx = -1e300;
        for (int k = 0; k < K; ++k) {
            double u = pv[k] / (stdv + 1e-8) / 0.3;
            pa[k] = -u * u;
            if (pa[k] > mx) mx = pa[k];
        }
        double es = 0.0, ev[K];
        for (int k = 0; k < K; ++k) { ev[k] = exp(pa[k] - mx); es += ev[k]; }
        for (int k = 0; k < K; ++k) pos.v[k] = (float)(ev[k] / es);
    }

    dim3 blk(256);
    k_img_down<<<(CI * HW2 + 255) / 256, blk, 0, stream>>>(imgs, imgs2);
    k_aff2<<<(HW2 * 64 + 255) / 256, blk, 0, stream>>>(imgs2, aff2);
    k_aff_total<<<(HW * 16 + 255) / 256, blk, 0, stream>>>(imgs, aff2, afft, pos);
    k_mask_up<<<(CM * HW + 255) / 256, blk, 0, stream>>>(masks, mA);

    float* bufs[2] = {mA, mB};
    const float* cur = mA;
    for (int i = 0; i < 10; ++i) {
        float* o = (i == 9) ? out : bufs[(i + 1) & 1];
        k_prop<<<4704, blk, 0, stream>>>(cur, afft, o);
        cur = o;
    }
}

// Round 11
// 237.729 us; speedup vs baseline: 1.1493x; 1.1493x over previous
//
#include <hip/hip_runtime.h>
#include <hip/hip_fp16.h>
#include <math.h>

namespace {
constexpr int IH = 224, IW = 224;
constexpr int H2 = 67, W2 = 67;
constexpr int MH = 56, MW = 56;
constexpr int CI = 3, CM = 21;
constexpr int ND = 6;
constexpr int K = 48;
constexpr int HW = IH * IW;    // 50176
constexpr int HW2 = H2 * W2;   // 4489
constexpr float EPS = 1e-8f;
__device__ __constant__ int DILS_C[ND] = {1, 2, 4, 8, 12, 24};
}

struct PosArr { float v[K]; };

__device__ __forceinline__ float wsum64(float v) {
    #pragma unroll
    for (int off = 1; off < 64; off <<= 1) v += __shfl_xor(v, off);
    return v;
}

// ---------------- bilinear downsample imgs 224->67 (align_corners) ----------
__global__ void k_img_down(const float* __restrict__ img, float* __restrict__ img2) {
    int t = blockIdx.x * blockDim.x + threadIdx.x;
    if (t >= CI * HW2) return;
    int c = t / HW2, r = t % HW2;
    int y = r / W2, x = r % W2;
    float fy = (float)y * ((float)(IH - 1) / (float)(H2 - 1));
    float fx = (float)x * ((float)(IW - 1) / (float)(W2 - 1));
    int y0 = (int)floorf(fy); int y1 = min(y0 + 1, IH - 1); float wy = fy - (float)y0;
    int x0 = (int)floorf(fx); int x1 = min(x0 + 1, IW - 1); float wx = fx - (float)x0;
    const float* p = img + c * HW;
    float v00 = p[y0 * IW + x0], v01 = p[y0 * IW + x1];
    float v10 = p[y1 * IW + x0], v11 = p[y1 * IW + x1];
    float r0 = v00 * (1.f - wy) + v10 * wy;
    float r1 = v01 * (1.f - wy) + v11 * wy;
    img2[t] = r0 * (1.f - wx) + r1 * wx;
}

// ---------------- low-res affinity: one WAVE per pixel ----------------------
__global__ void k_aff2(const float* __restrict__ img2, float* __restrict__ aff2) {
    int gtid = blockIdx.x * blockDim.x + threadIdx.x;
    int wave = gtid >> 6;
    int lane = threadIdx.x & 63;
    if (wave >= HW2) return;
    int t = wave;
    int y = t / W2, x = t % W2;

    int k = (lane < K) ? lane : (K - 1);
    int di = k >> 3, o = k & 7;
    int d = DILS_C[di];
    int ym = max(y - d, 0), yp = min(y + d, H2 - 1);
    int xm = max(x - d, 0), xp = min(x + d, W2 - 1);
    int ki = (0x22211000u >> (o * 4)) & 3;
    int kj = (0x21020210u >> (o * 4)) & 3;
    int ry = ki == 0 ? ym : (ki == 1 ? y : yp);
    int rx = kj == 0 ? xm : (kj == 1 ? x : xp);
    int nidx = ry * W2 + rx;

    float av = 0.f;
    #pragma unroll
    for (int c = 0; c < CI; ++c) {
        const float* p = img2 + c * HW2;
        float center = p[y * W2 + x];
        float v = p[nidx];
        float vv = (lane < K) ? v : 0.f;
        float s = wsum64(vv);
        float s2 = wsum64(vv * vv);
        float mean = s * (1.f / (float)K);
        float ss = s2 - (float)K * mean * mean;
        float stdv = sqrtf(fmaxf(ss, 0.f) * (1.f / (float)(K - 1)));
        float inv = 1.f / (stdv + EPS);
        float tt = fabsf(v - center) * inv;
        av += tt * tt;
    }
    if (lane < K) aff2[(size_t)t * K + k] = av;
}

// ---------------- full-res aff + upsampled aff2 + pos -> aff_total ----------
// 16 lanes per pixel; writes afft[t*K + k] as FP16
__global__ void k_aff_total(const float* __restrict__ img,
                            const float* __restrict__ aff2,
                            __half* __restrict__ afft, PosArr pos) {
    int gid = blockIdx.x * blockDim.x + threadIdx.x;
    int t = gid >> 4;
    int lane = threadIdx.x & 15;
    if (t >= HW) return;
    int y = t / IW, x = t % IW;

    int nidx[3];
    int kk[3];
    #pragma unroll
    for (int s = 0; s < 3; ++s) {
        int k = lane + 16 * s;
        kk[s] = k;
        int di = k >> 3, o = k & 7;
        int d = DILS_C[di];
        int ki = (0x22211000u >> (o * 4)) & 3;
        int kj = (0x21020210u >> (o * 4)) & 3;
        int ym = max(y - d, 0), yp = min(y + d, IH - 1);
        int xm = max(x - d, 0), xp = min(x + d, IW - 1);
        int ry = ki == 0 ? ym : (ki == 1 ? y : yp);
        int rx = kj == 0 ? xm : (kj == 1 ? x : xp);
        nidx[s] = ry * IW + rx;
    }

    float av0 = 0.f, av1 = 0.f, av2 = 0.f;
    #pragma unroll
    for (int c = 0; c < CI; ++c) {
        const float* p = img + c * HW;
        float center = p[y * IW + x];
        float n0 = p[nidx[0]], n1 = p[nidx[1]], n2 = p[nidx[2]];
        float s1 = n0 + n1 + n2;
        float s2 = n0 * n0 + n1 * n1 + n2 * n2;
        #pragma unroll
        for (int off = 1; off < 16; off <<= 1) {
            s1 += __shfl_xor(s1, off, 16);
            s2 += __shfl_xor(s2, off, 16);
        }
        float mean = s1 * (1.f / (float)K);
        float ss = s2 - (float)K * mean * mean;
        float inv = 1.f / (sqrtf(fmaxf(ss, 0.f) * (1.f / (float)(K - 1))) + EPS);
        float t0 = fabsf(n0 - center) * inv; av0 += t0 * t0;
        float t1 = fabsf(n1 - center) * inv; av1 += t1 * t1;
        float t2 = fabsf(n2 - center) * inv; av2 += t2 * t2;
    }
    const float sc = -(1.f / (float)CI) / (0.3f * 0.3f);
    av0 *= sc; av1 *= sc; av2 *= sc;
    float m1 = fmaxf(av0, fmaxf(av1, av2));
    #pragma unroll
    for (int off = 1; off < 16; off <<= 1) m1 = fmaxf(m1, __shfl_xor(m1, off, 16));
    float e0 = expf(av0 - m1), e1 = expf(av1 - m1), e2 = expf(av2 - m1);
    float es = e0 + e1 + e2;
    #pragma unroll
    for (int off = 1; off < 16; off <<= 1) es += __shfl_xor(es, off, 16);
    float r1 = 1.f / es;

    float fy = (float)y * ((float)(H2 - 1) / (float)(IH - 1));
    float fx = (float)x * ((float)(W2 - 1) / (float)(IW - 1));
    int y0 = (int)floorf(fy); int y1 = min(y0 + 1, H2 - 1); float wy = fy - (float)y0;
    int x0 = (int)floorf(fx); int x1 = min(x0 + 1, W2 - 1); float wx = fx - (float)x0;
    const float* q00 = aff2 + (size_t)(y0 * W2 + x0) * K;
    const float* q01 = aff2 + (size_t)(y0 * W2 + x1) * K;
    const float* q10 = aff2 + (size_t)(y1 * W2 + x0) * K;
    const float* q11 = aff2 + (size_t)(y1 * W2 + x1) * K;
    float w00 = (1.f - wy) * (1.f - wx), w01 = (1.f - wy) * wx;
    float w10 = wy * (1.f - wx), w11 = wy * wx;
    const float sc2 = -(1.f / (float)CI);
    float b0 = (q00[kk[0]] * w00 + q01[kk[0]] * w01 + q10[kk[0]] * w10 + q11[kk[0]] * w11) * sc2;
    float b1 = (q00[kk[1]] * w00 + q01[kk[1]] * w01 + q10[kk[1]] * w10 + q11[kk[1]] * w11) * sc2;
    float b2 = (q00[kk[2]] * w00 + q01[kk[2]] * w01 + q10[kk[2]] * w10 + q11[kk[2]] * w11) * sc2;
    float m2 = fmaxf(b0, fmaxf(b1, b2));
    #pragma unroll
    for (int off = 1; off < 16; off <<= 1) m2 = fmaxf(m2, __shfl_xor(m2, off, 16));
    float f0 = expf(b0 - m2), f1 = expf(b1 - m2), f2 = expf(b2 - m2);
    float fs = f0 + f1 + f2;
    #pragma unroll
    for (int off = 1; off < 16; off <<= 1) fs += __shfl_xor(fs, off, 16);
    float r2 = 1.f / fs;

    __half* o = afft + (size_t)t * K;
    o[kk[0]] = __float2half(e0 * r1 + f0 * r2 + pos.v[kk[0]]);
    o[kk[1]] = __float2half(e1 * r1 + f1 * r2 + pos.v[kk[1]]);
    o[kk[2]] = __float2half(e2 * r1 + f2 * r2 + pos.v[kk[2]]);
}

// ---------------- mask upsample 56 -> 224 -----------------------------------
__global__ void k_mask_up(const float* __restrict__ m, float* __restrict__ mu) {
    int t = blockIdx.x * blockDim.x + threadIdx.x;
    if (t >= CM * HW) return;
    int c = t / HW, r = t % HW;
    int y = r / IW, x = r % IW;
    float fy = (float)y * ((float)(MH - 1) / (float)(IH - 1));
    float fx = (float)x * ((float)(MW - 1) / (float)(IW - 1));
    int y0 = (int)floorf(fy); int y1 = min(y0 + 1, MH - 1); float wy = fy - (float)y0;
    int x0 = (int)floorf(fx); int x1 = min(x0 + 1, MW - 1); float wx = fx - (float)x0;
    const float* p = m + c * MH * MW;
    float v00 = p[y0 * MW + x0], v01 = p[y0 * MW + x1];
    float v10 = p[y1 * MW + x0], v11 = p[y1 * MW + x1];
    float r0 = v00 * (1.f - wy) + v10 * wy;
    float r1 = v01 * (1.f - wy) + v11 * wy;
    mu[t] = r0 * (1.f - wx) + r1 * wx;
}

// ---------------- one propagation iteration (3-unit pipelined) --------------
// Block handles 3 (y,c) units with ONE 11.6 KB LDS buffer (8 blocks/CU).
// Per unit: issue next unit's global loads into regs -> compute current unit
// from LDS (R7 body, unchanged) -> barrier -> ds_write staged regs -> barrier.
// Staging latency hides under compute (T14 split). Grid 1568 = whole grid
// co-resident (6.1 blk/CU), XCD-swizzled as before.
__global__ __launch_bounds__(256, 8) void k_prop(const float* __restrict__ min_,
                                                 const __half* __restrict__ afft,
                                                 float* __restrict__ mout) {
    __shared__ float L[13 * 224];   // 11648 B
    const int tid = threadIdx.x;
    const int b = blockIdx.x;
    const int base = (b & 7) * 588 + (b >> 3);   // + j*196, j=0..2 -> bijective
    const int ROW_DY[13] = {-24, -12, -8, -4, -2, -1, 0, 1, 2, 4, 8, 12, 24};

    // ---- prologue: stage unit 0
    {
        int sw = base;
        int y = sw / 21, c = sw - y * 21;
        const float* mc = min_ + (size_t)c * HW;
        for (int i = tid; i < 13 * 56; i += 256) {
            int r = i / 56, q = i - r * 56;
            int gy = min(max(y + ROW_DY[r], 0), IH - 1);
            *(float4*)(L + r * 224 + q * 4) = ((const float4*)(mc + gy * IW))[q];
        }
    }
    __syncthreads();

    #pragma unroll
    for (int j = 0; j < 3; ++j) {
        const int sw = base + j * 196;
        const int y = sw / 21, c = sw - y * 21;

        // issue next-unit staging loads into registers (latency hides under compute)
        float4 s0, s1, s2;
        if (j < 2) {
            int sw2 = base + (j + 1) * 196;
            int y2 = sw2 / 21, c2 = sw2 - y2 * 21;
            const float* mc2 = min_ + (size_t)c2 * HW;
            {
                int i = tid; int r = i / 56, q = i - r * 56;
                int gy = min(max(y2 + ROW_DY[r], 0), IH - 1);
                s0 = ((const float4*)(mc2 + gy * IW))[q];
            }
            {
                int i = tid + 256; int r = i / 56, q = i - r * 56;
                int gy = min(max(y2 + ROW_DY[r], 0), IH - 1);
                s1 = ((const float4*)(mc2 + gy * IW))[q];
            }
            if (tid < 216) {
                int i = tid + 512; int r = i / 56, q = i - r * 56;
                int gy = min(max(y2 + ROW_DY[r], 0), IH - 1);
                s2 = ((const float4*)(mc2 + gy * IW))[q];
            }
        }

        // compute unit j (identical to R7 body)
        if (tid < IW) {
            const int x = tid;
            const int t = y * IW + x;
            uint4 w[6];
            {
                const uint4* aw = (const uint4*)(afft + (size_t)t * K);  // 96 B
                #pragma unroll
                for (int i = 0; i < 6; ++i) w[i] = aw[i];
            }
            const int DILS[ND] = {1, 2, 4, 8, 12, 24};
            const int RMI[ND] = {5, 4, 3, 2, 1, 0};
            const int RPI[ND] = {7, 8, 9, 10, 11, 12};
            const float* Lc = L + 6 * 224;
            float acc = 0.f;
            #pragma unroll
            for (int di = 0; di < ND; ++di) {
                int d = DILS[di];
                int cm = max(x - d, 0);
                int cp = min(x + d, IW - 1);
                const float* Lm = L + RMI[di] * 224;
                const float* Lp = L + RPI[di] * 224;
                const __half2* hp = (const __half2*)&w[di];
                float2 f01 = __half22float2(hp[0]);
                float2 f23 = __half22float2(hp[1]);
                float2 f45 = __half22float2(hp[2]);
                float2 f67 = __half22float2(hp[3]);
                acc += Lm[cm] * f01.x;
                acc += Lm[x]  * f01.y;
                acc += Lm[cp] * f23.x;
                acc += Lc[cm] * f23.y;
                acc += Lc[cp] * f45.x;
                acc += Lp[cm] * f45.y;
                acc += Lp[x]  * f67.x;
                acc += Lp[cp] * f67.y;
            }
            mout[(size_t)c * HW + t] = acc;
        }

        if (j < 2) {
            __syncthreads();   // all reads of L for unit j complete
            {
                int i = tid; int r = i / 56, q = i - r * 56;
                *(float4*)(L + r * 224 + q * 4) = s0;
            }
            {
                int i = tid + 256; int r = i / 56, q = i - r * 56;
                *(float4*)(L + r * 224 + q * 4) = s1;
            }
            if (tid < 216) {
                int i = tid + 512; int r = i / 56, q = i - r * 56;
                *(float4*)(L + r * 224 + q * 4) = s2;
            }
            __syncthreads();   // L ready for unit j+1
        }
    }
}

extern "C" void kernel_launch(void* const* d_in, const int* in_sizes, int n_in,
                              void* d_out, int out_size, void* d_ws, size_t ws_size,
                              hipStream_t stream) {
    const float* imgs  = (const float*)d_in[0];
    const float* masks = (const float*)d_in[1];
    float* out = (float*)d_out;

    float* ws = (float*)d_ws;
    float* imgs2 = ws;                       // CI*HW2 = 13467 -> pad to 16384
    float* aff2  = imgs2 + 16384;            // HW2*K  = 215472 (layout [HW2][K])
    __half* afft = (__half*)(aff2 + K * HW2);       // HW*K halfs = 4.8 MB
    float* mA    = aff2 + K * HW2 + (K * HW) / 2;   // CM*HW floats
    float* mB    = mA + (size_t)CM * HW;

    // host-side positional softmax (input-independent, same every call)
    PosArr pos;
    {
        double pv[K];
        const int dil[ND] = {1, 2, 4, 8, 12, 24};
        const double s2 = sqrt(2.0);
        for (int di = 0; di < ND; ++di)
            for (int o = 0; o < 8; ++o) {
                double base = (o == 0 || o == 2 || o == 5 || o == 7) ? s2 : 1.0;
                pv[di * 8 + o] = base * (double)dil[di];
            }
        double sum = 0.0; for (int k = 0; k < K; ++k) sum += pv[k];
        double mean = sum / K;
        double ssd = 0.0; for (int k = 0; k < K; ++k) { double d0 = pv[k] - mean; ssd += d0 * d0; }
        double stdv = sqrt(ssd / (K - 1));
        double pa[K];
        double mx = -1e300;
        for (int k = 0; k < K; ++k) {
            double u = pv[k] / (stdv + 1e-8) / 0.3;
            pa[k] = -u * u;
            if (pa[k] > mx) mx = pa[k];
        }
        double es = 0.0, ev[K];
        for (int k = 0; k < K; ++k) { ev[k] = exp(pa[k] - mx); es += ev[k]; }
        for (int k = 0; k < K; ++k) pos.v[k] = (float)(ev[k] / es);
    }

    dim3 blk(256);
    k_img_down<<<(CI * HW2 + 255) / 256, blk, 0, stream>>>(imgs, imgs2);
    k_aff2<<<(HW2 * 64 + 255) / 256, blk, 0, stream>>>(imgs2, aff2);
    k_aff_total<<<(HW * 16 + 255) / 256, blk, 0, stream>>>(imgs, aff2, afft, pos);
    k_mask_up<<<(CM * HW + 255) / 256, blk, 0, stream>>>(masks, mA);

    float* bufs[2] = {mA, mB};
    const float* cur = mA;
    for (int i = 0; i < 10; ++i) {
        float* o = (i == 9) ? out : bufs[(i + 1) & 1];
        k_prop<<<1568, blk, 0, stream>>>(cur, afft, o);
        cur = o;
    }
}

// Round 12
// 189.868 us; speedup vs baseline: 1.4390x; 1.2521x over previous
//
#include <hip/hip_runtime.h>
#include <hip/hip_fp16.h>
#include <math.h>

namespace {
constexpr int IH = 224, IW = 224;
constexpr int H2 = 67, W2 = 67;
constexpr int MH = 56, MW = 56;
constexpr int CI = 3, CM = 21;
constexpr int ND = 6;
constexpr int K = 48;
constexpr int HW = IH * IW;    // 50176
constexpr int HW2 = H2 * W2;   // 4489
constexpr float EPS = 1e-8f;
__device__ __constant__ int DILS_C[ND] = {1, 2, 4, 8, 12, 24};
}

struct PosArr { float v[K]; };

__device__ __forceinline__ float wsum64(float v) {
    #pragma unroll
    for (int off = 1; off < 64; off <<= 1) v += __shfl_xor(v, off);
    return v;
}

// direct global->LDS 16B copy (CK/m97 pattern; LDS dest must be linear in lane order)
__device__ __forceinline__ void gload_lds16(const float* g, float* l) {
    __builtin_amdgcn_global_load_lds(
        (const __attribute__((address_space(1))) void*)(g),
        (__attribute__((address_space(3))) void*)(l), 16, 0, 0);
}

// ---------------- prep: img downsample 224->67  +  mask upsample 56->224 ----
__global__ void k_prep(const float* __restrict__ img, float* __restrict__ img2,
                       const float* __restrict__ m, float* __restrict__ mu) {
    int t = blockIdx.x * blockDim.x + threadIdx.x;
    if (t < CI * HW2) {
        int c = t / HW2, r = t % HW2;
        int y = r / W2, x = r % W2;
        float fy = (float)y * ((float)(IH - 1) / (float)(H2 - 1));
        float fx = (float)x * ((float)(IW - 1) / (float)(W2 - 1));
        int y0 = (int)floorf(fy); int y1 = min(y0 + 1, IH - 1); float wy = fy - (float)y0;
        int x0 = (int)floorf(fx); int x1 = min(x0 + 1, IW - 1); float wx = fx - (float)x0;
        const float* p = img + c * HW;
        float v00 = p[y0 * IW + x0], v01 = p[y0 * IW + x1];
        float v10 = p[y1 * IW + x0], v11 = p[y1 * IW + x1];
        float r0 = v00 * (1.f - wy) + v10 * wy;
        float r1 = v01 * (1.f - wy) + v11 * wy;
        img2[t] = r0 * (1.f - wx) + r1 * wx;
    }
    if (t < CM * HW) {
        int c = t / HW, r = t % HW;
        int y = r / IW, x = r % IW;
        float fy = (float)y * ((float)(MH - 1) / (float)(IH - 1));
        float fx = (float)x * ((float)(MW - 1) / (float)(IW - 1));
        int y0 = (int)floorf(fy); int y1 = min(y0 + 1, MH - 1); float wy = fy - (float)y0;
        int x0 = (int)floorf(fx); int x1 = min(x0 + 1, MW - 1); float wx = fx - (float)x0;
        const float* p = m + c * MH * MW;
        float v00 = p[y0 * MW + x0], v01 = p[y0 * MW + x1];
        float v10 = p[y1 * MW + x0], v11 = p[y1 * MW + x1];
        float r0 = v00 * (1.f - wy) + v10 * wy;
        float r1 = v01 * (1.f - wy) + v11 * wy;
        mu[t] = r0 * (1.f - wx) + r1 * wx;
    }
}

// ---------------- low-res affinity: one WAVE per pixel ----------------------
__global__ void k_aff2(const float* __restrict__ img2, float* __restrict__ aff2) {
    int gtid = blockIdx.x * blockDim.x + threadIdx.x;
    int wave = gtid >> 6;
    int lane = threadIdx.x & 63;
    if (wave >= HW2) return;
    int t = wave;
    int y = t / W2, x = t % W2;

    int k = (lane < K) ? lane : (K - 1);
    int di = k >> 3, o = k & 7;
    int d = DILS_C[di];
    int ym = max(y - d, 0), yp = min(y + d, H2 - 1);
    int xm = max(x - d, 0), xp = min(x + d, W2 - 1);
    int ki = (0x22211000u >> (o * 4)) & 3;
    int kj = (0x21020210u >> (o * 4)) & 3;
    int ry = ki == 0 ? ym : (ki == 1 ? y : yp);
    int rx = kj == 0 ? xm : (kj == 1 ? x : xp);
    int nidx = ry * W2 + rx;

    float av = 0.f;
    #pragma unroll
    for (int c = 0; c < CI; ++c) {
        const float* p = img2 + c * HW2;
        float center = p[y * W2 + x];
        float v = p[nidx];
        float vv = (lane < K) ? v : 0.f;
        float s = wsum64(vv);
        float s2 = wsum64(vv * vv);
        float mean = s * (1.f / (float)K);
        float ss = s2 - (float)K * mean * mean;
        float stdv = sqrtf(fmaxf(ss, 0.f) * (1.f / (float)(K - 1)));
        float inv = 1.f / (stdv + EPS);
        float tt = fabsf(v - center) * inv;
        av += tt * tt;
    }
    if (lane < K) aff2[(size_t)t * K + k] = av;
}

// ---------------- full-res aff + upsampled aff2 + pos -> aff_total ----------
// 16 lanes per pixel; writes afft[t*K + k] as FP16
__global__ void k_aff_total(const float* __restrict__ img,
                            const float* __restrict__ aff2,
                            __half* __restrict__ afft, PosArr pos) {
    int gid = blockIdx.x * blockDim.x + threadIdx.x;
    int t = gid >> 4;
    int lane = threadIdx.x & 15;
    if (t >= HW) return;
    int y = t / IW, x = t % IW;

    int nidx[3];
    int kk[3];
    #pragma unroll
    for (int s = 0; s < 3; ++s) {
        int k = lane + 16 * s;
        kk[s] = k;
        int di = k >> 3, o = k & 7;
        int d = DILS_C[di];
        int ki = (0x22211000u >> (o * 4)) & 3;
        int kj = (0x21020210u >> (o * 4)) & 3;
        int ym = max(y - d, 0), yp = min(y + d, IH - 1);
        int xm = max(x - d, 0), xp = min(x + d, IW - 1);
        int ry = ki == 0 ? ym : (ki == 1 ? y : yp);
        int rx = kj == 0 ? xm : (kj == 1 ? x : xp);
        nidx[s] = ry * IW + rx;
    }

    float av0 = 0.f, av1 = 0.f, av2 = 0.f;
    #pragma unroll
    for (int c = 0; c < CI; ++c) {
        const float* p = img + c * HW;
        float center = p[y * IW + x];
        float n0 = p[nidx[0]], n1 = p[nidx[1]], n2 = p[nidx[2]];
        float s1 = n0 + n1 + n2;
        float s2 = n0 * n0 + n1 * n1 + n2 * n2;
        #pragma unroll
        for (int off = 1; off < 16; off <<= 1) {
            s1 += __shfl_xor(s1, off, 16);
            s2 += __shfl_xor(s2, off, 16);
        }
        float mean = s1 * (1.f / (float)K);
        float ss = s2 - (float)K * mean * mean;
        float inv = 1.f / (sqrtf(fmaxf(ss, 0.f) * (1.f / (float)(K - 1))) + EPS);
        float t0 = fabsf(n0 - center) * inv; av0 += t0 * t0;
        float t1 = fabsf(n1 - center) * inv; av1 += t1 * t1;
        float t2 = fabsf(n2 - center) * inv; av2 += t2 * t2;
    }
    const float sc = -(1.f / (float)CI) / (0.3f * 0.3f);
    av0 *= sc; av1 *= sc; av2 *= sc;
    float m1 = fmaxf(av0, fmaxf(av1, av2));
    #pragma unroll
    for (int off = 1; off < 16; off <<= 1) m1 = fmaxf(m1, __shfl_xor(m1, off, 16));
    float e0 = expf(av0 - m1), e1 = expf(av1 - m1), e2 = expf(av2 - m1);
    float es = e0 + e1 + e2;
    #pragma unroll
    for (int off = 1; off < 16; off <<= 1) es += __shfl_xor(es, off, 16);
    float r1 = 1.f / es;

    float fy = (float)y * ((float)(H2 - 1) / (float)(IH - 1));
    float fx = (float)x * ((float)(W2 - 1) / (float)(IW - 1));
    int y0 = (int)floorf(fy); int y1 = min(y0 + 1, H2 - 1); float wy = fy - (float)y0;
    int x0 = (int)floorf(fx); int x1 = min(x0 + 1, W2 - 1); float wx = fx - (float)x0;
    const float* q00 = aff2 + (size_t)(y0 * W2 + x0) * K;
    const float* q01 = aff2 + (size_t)(y0 * W2 + x1) * K;
    const float* q10 = aff2 + (size_t)(y1 * W2 + x0) * K;
    const float* q11 = aff2 + (size_t)(y1 * W2 + x1) * K;
    float w00 = (1.f - wy) * (1.f - wx), w01 = (1.f - wy) * wx;
    float w10 = wy * (1.f - wx), w11 = wy * wx;
    const float sc2 = -(1.f / (float)CI);
    float b0 = (q00[kk[0]] * w00 + q01[kk[0]] * w01 + q10[kk[0]] * w10 + q11[kk[0]] * w11) * sc2;
    float b1 = (q00[kk[1]] * w00 + q01[kk[1]] * w01 + q10[kk[1]] * w10 + q11[kk[1]] * w11) * sc2;
    float b2 = (q00[kk[2]] * w00 + q01[kk[2]] * w01 + q10[kk[2]] * w10 + q11[kk[2]] * w11) * sc2;
    float m2 = fmaxf(b0, fmaxf(b1, b2));
    #pragma unroll
    for (int off = 1; off < 16; off <<= 1) m2 = fmaxf(m2, __shfl_xor(m2, off, 16));
    float f0 = expf(b0 - m2), f1 = expf(b1 - m2), f2 = expf(b2 - m2);
    float fs = f0 + f1 + f2;
    #pragma unroll
    for (int off = 1; off < 16; off <<= 1) fs += __shfl_xor(fs, off, 16);
    float r2 = 1.f / fs;

    __half* o = afft + (size_t)t * K;
    o[kk[0]] = __float2half(e0 * r1 + f0 * r2 + pos.v[kk[0]]);
    o[kk[1]] = __float2half(e1 * r1 + f1 * r2 + pos.v[kk[1]]);
    o[kk[2]] = __float2half(e2 * r1 + f2 * r2 + pos.v[kk[2]]);
}

// ---------------- one propagation iteration ---------------------------------
// R7 structure exactly (block = (row y, channel c), 11.6 KB LDS, 8 blk/CU,
// weights hoisted before the barrier) with ONE change: staging uses
// global_load_lds (direct L2->LDS, no VGPR round-trip, no ds_write).
// LDS slot i (16B) is linear in lane order -> satisfies the wave-uniform-
// base + lane*16 layout requirement. Grid 4704, XCD-swizzled.
__global__ __launch_bounds__(256) void k_prop(const float* __restrict__ min_,
                                              const __half* __restrict__ afft,
                                              float* __restrict__ mout) {
    __shared__ float L[13 * 224];   // 11648 B = 728 x 16B slots
    int tid = threadIdx.x;
    int bid = blockIdx.x;
    int sw = (bid & 7) * 588 + (bid >> 3);   // 4704 = 8 * 588, bijective
    int y = sw / 21;
    int c = sw - y * 21;

    // hoist affinity-weight loads (latency hides under staging)
    int x = min(tid, IW - 1);
    int t = y * IW + x;
    uint4 w[6];
    {
        const uint4* aw = (const uint4*)(afft + (size_t)t * K);  // 96 B
        #pragma unroll
        for (int i = 0; i < 6; ++i) w[i] = aw[i];
    }

    // stage 13 rows x 224 px of channel c: 728 16B slots, direct global->LDS
    const int ROW_DY[13] = {-24, -12, -8, -4, -2, -1, 0, 1, 2, 4, 8, 12, 24};
    const float* mc = min_ + (size_t)c * HW;
    {
        int i = tid;                       // slots 0..255
        int r = i / 56, q = i - r * 56;
        int gy = min(max(y + ROW_DY[r], 0), IH - 1);
        gload_lds16(mc + gy * IW + q * 4, L + i * 4);
    }
    {
        int i = tid + 256;                 // slots 256..511
        int r = i / 56, q = i - r * 56;
        int gy = min(max(y + ROW_DY[r], 0), IH - 1);
        gload_lds16(mc + gy * IW + q * 4, L + i * 4);
    }
    if (tid < 216) {
        int i = tid + 512;                 // slots 512..727
        int r = i / 56, q = i - r * 56;
        int gy = min(max(y + ROW_DY[r], 0), IH - 1);
        gload_lds16(mc + gy * IW + q * 4, L + i * 4);
    }
    __syncthreads();

    if (tid >= IW) return;

    const int DILS[ND] = {1, 2, 4, 8, 12, 24};
    const int RMI[ND] = {5, 4, 3, 2, 1, 0};
    const int RPI[ND] = {7, 8, 9, 10, 11, 12};
    const float* Lc = L + 6 * 224;

    float acc = 0.f;
    #pragma unroll
    for (int di = 0; di < ND; ++di) {
        int d = DILS[di];
        int cm = max(x - d, 0);
        int cp = min(x + d, IW - 1);
        const float* Lm = L + RMI[di] * 224;
        const float* Lp = L + RPI[di] * 224;
        const __half2* hp = (const __half2*)&w[di];
        float2 f01 = __half22float2(hp[0]);
        float2 f23 = __half22float2(hp[1]);
        float2 f45 = __half22float2(hp[2]);
        float2 f67 = __half22float2(hp[3]);
        acc += Lm[cm] * f01.x;
        acc += Lm[x]  * f01.y;
        acc += Lm[cp] * f23.x;
        acc += Lc[cm] * f23.y;
        acc += Lc[cp] * f45.x;
        acc += Lp[cm] * f45.y;
        acc += Lp[x]  * f67.x;
        acc += Lp[cp] * f67.y;
    }
    mout[(size_t)c * HW + t] = acc;
}

extern "C" void kernel_launch(void* const* d_in, const int* in_sizes, int n_in,
                              void* d_out, int out_size, void* d_ws, size_t ws_size,
                              hipStream_t stream) {
    const float* imgs  = (const float*)d_in[0];
    const float* masks = (const float*)d_in[1];
    float* out = (float*)d_out;

    float* ws = (float*)d_ws;
    float* imgs2 = ws;                       // CI*HW2 = 13467 -> pad to 16384
    float* aff2  = imgs2 + 16384;            // HW2*K  = 215472 (layout [HW2][K])
    __half* afft = (__half*)(aff2 + K * HW2);       // HW*K halfs = 4.8 MB
    float* mA    = aff2 + K * HW2 + (K * HW) / 2;   // CM*HW floats
    float* mB    = mA + (size_t)CM * HW;

    // host-side positional softmax (input-independent, same every call)
    PosArr pos;
    {
        double pv[K];
        const int dil[ND] = {1, 2, 4, 8, 12, 24};
        const double s2 = sqrt(2.0);
        for (int di = 0; di < ND; ++di)
            for (int o = 0; o < 8; ++o) {
                double base = (o == 0 || o == 2 || o == 5 || o == 7) ? s2 : 1.0;
                pv[di * 8 + o] = base * (double)dil[di];
            }
        double sum = 0.0; for (int k = 0; k < K; ++k) sum += pv[k];
        double mean = sum / K;
        double ssd = 0.0; for (int k = 0; k < K; ++k) { double d0 = pv[k] - mean; ssd += d0 * d0; }
        double stdv = sqrt(ssd / (K - 1));
        double pa[K];
        double mx = -1e300;
        for (int k = 0; k < K; ++k) {
            double u = pv[k] / (stdv + 1e-8) / 0.3;
            pa[k] = -u * u;
            if (pa[k] > mx) mx = pa[k];
        }
        double es = 0.0, ev[K];
        for (int k = 0; k < K; ++k) { ev[k] = exp(pa[k] - mx); es += ev[k]; }
        for (int k = 0; k < K; ++k) pos.v[k] = (float)(ev[k] / es);
    }

    dim3 blk(256);
    k_prep<<<(CM * HW + 255) / 256, blk, 0, stream>>>(imgs, imgs2, masks, mA);
    k_aff2<<<(HW2 * 64 + 255) / 256, blk, 0, stream>>>(imgs2, aff2);
    k_aff_total<<<(HW * 16 + 255) / 256, blk, 0, stream>>>(imgs, aff2, afft, pos);

    float* bufs[2] = {mA, mB};
    const float* cur = mA;
    for (int i = 0; i < 10; ++i) {
        float* o = (i == 9) ? out : bufs[(i + 1) & 1];
        k_prop<<<4704, blk, 0, stream>>>(cur, afft, o);
        cur = o;
    }
}

// Round 13
// 170.305 us; speedup vs baseline: 1.6043x; 1.1149x over previous
//
#include <hip/hip_runtime.h>
#include <hip/hip_fp16.h>
#include <math.h>

namespace {
constexpr int IH = 224, IW = 224;
constexpr int H2 = 67, W2 = 67;
constexpr int MH = 56, MW = 56;
constexpr int CI = 3, CM = 21;
constexpr int ND = 6;
constexpr int K = 48;
constexpr int HW = IH * IW;    // 50176
constexpr int HW2 = H2 * W2;   // 4489
constexpr float EPS = 1e-8f;
__device__ __constant__ int DILS_C[ND] = {1, 2, 4, 8, 12, 24};
}

struct PosArr { float v[K]; };

__device__ __forceinline__ float wsum64(float v) {
    #pragma unroll
    for (int off = 1; off < 64; off <<= 1) v += __shfl_xor(v, off);
    return v;
}

// direct global->LDS 16B copy (LDS dest must be linear in lane order)
__device__ __forceinline__ void gload_lds16(const void* g, void* l) {
    __builtin_amdgcn_global_load_lds(
        (const __attribute__((address_space(1))) void*)(g),
        (__attribute__((address_space(3))) void*)(l), 16, 0, 0);
}

// ---------------- prep: img downsample 224->67  +  mask upsample 56->224 ----
// mask output stored FP16 (propagation state dtype)
__global__ void k_prep(const float* __restrict__ img, float* __restrict__ img2,
                       const float* __restrict__ m, __half* __restrict__ mu) {
    int t = blockIdx.x * blockDim.x + threadIdx.x;
    if (t < CI * HW2) {
        int c = t / HW2, r = t % HW2;
        int y = r / W2, x = r % W2;
        float fy = (float)y * ((float)(IH - 1) / (float)(H2 - 1));
        float fx = (float)x * ((float)(IW - 1) / (float)(W2 - 1));
        int y0 = (int)floorf(fy); int y1 = min(y0 + 1, IH - 1); float wy = fy - (float)y0;
        int x0 = (int)floorf(fx); int x1 = min(x0 + 1, IW - 1); float wx = fx - (float)x0;
        const float* p = img + c * HW;
        float v00 = p[y0 * IW + x0], v01 = p[y0 * IW + x1];
        float v10 = p[y1 * IW + x0], v11 = p[y1 * IW + x1];
        float r0 = v00 * (1.f - wy) + v10 * wy;
        float r1 = v01 * (1.f - wy) + v11 * wy;
        img2[t] = r0 * (1.f - wx) + r1 * wx;
    }
    if (t < CM * HW) {
        int c = t / HW, r = t % HW;
        int y = r / IW, x = r % IW;
        float fy = (float)y * ((float)(MH - 1) / (float)(IH - 1));
        float fx = (float)x * ((float)(MW - 1) / (float)(IW - 1));
        int y0 = (int)floorf(fy); int y1 = min(y0 + 1, MH - 1); float wy = fy - (float)y0;
        int x0 = (int)floorf(fx); int x1 = min(x0 + 1, MW - 1); float wx = fx - (float)x0;
        const float* p = m + c * MH * MW;
        float v00 = p[y0 * MW + x0], v01 = p[y0 * MW + x1];
        float v10 = p[y1 * MW + x0], v11 = p[y1 * MW + x1];
        float r0 = v00 * (1.f - wy) + v10 * wy;
        float r1 = v01 * (1.f - wy) + v11 * wy;
        mu[t] = __float2half(r0 * (1.f - wx) + r1 * wx);
    }
}

// ---------------- low-res affinity: one WAVE per pixel ----------------------
__global__ void k_aff2(const float* __restrict__ img2, float* __restrict__ aff2) {
    int gtid = blockIdx.x * blockDim.x + threadIdx.x;
    int wave = gtid >> 6;
    int lane = threadIdx.x & 63;
    if (wave >= HW2) return;
    int t = wave;
    int y = t / W2, x = t % W2;

    int k = (lane < K) ? lane : (K - 1);
    int di = k >> 3, o = k & 7;
    int d = DILS_C[di];
    int ym = max(y - d, 0), yp = min(y + d, H2 - 1);
    int xm = max(x - d, 0), xp = min(x + d, W2 - 1);
    int ki = (0x22211000u >> (o * 4)) & 3;
    int kj = (0x21020210u >> (o * 4)) & 3;
    int ry = ki == 0 ? ym : (ki == 1 ? y : yp);
    int rx = kj == 0 ? xm : (kj == 1 ? x : xp);
    int nidx = ry * W2 + rx;

    float av = 0.f;
    #pragma unroll
    for (int c = 0; c < CI; ++c) {
        const float* p = img2 + c * HW2;
        float center = p[y * W2 + x];
        float v = p[nidx];
        float vv = (lane < K) ? v : 0.f;
        float s = wsum64(vv);
        float s2 = wsum64(vv * vv);
        float mean = s * (1.f / (float)K);
        float ss = s2 - (float)K * mean * mean;
        float stdv = sqrtf(fmaxf(ss, 0.f) * (1.f / (float)(K - 1)));
        float inv = 1.f / (stdv + EPS);
        float tt = fabsf(v - center) * inv;
        av += tt * tt;
    }
    if (lane < K) aff2[(size_t)t * K + k] = av;
}

// ---------------- full-res aff + upsampled aff2 + pos -> aff_total ----------
// 16 lanes per pixel; writes afft[t*K + k] as FP16
__global__ void k_aff_total(const float* __restrict__ img,
                            const float* __restrict__ aff2,
                            __half* __restrict__ afft, PosArr pos) {
    int gid = blockIdx.x * blockDim.x + threadIdx.x;
    int t = gid >> 4;
    int lane = threadIdx.x & 15;
    if (t >= HW) return;
    int y = t / IW, x = t % IW;

    int nidx[3];
    int kk[3];
    #pragma unroll
    for (int s = 0; s < 3; ++s) {
        int k = lane + 16 * s;
        kk[s] = k;
        int di = k >> 3, o = k & 7;
        int d = DILS_C[di];
        int ki = (0x22211000u >> (o * 4)) & 3;
        int kj = (0x21020210u >> (o * 4)) & 3;
        int ym = max(y - d, 0), yp = min(y + d, IH - 1);
        int xm = max(x - d, 0), xp = min(x + d, IW - 1);
        int ry = ki == 0 ? ym : (ki == 1 ? y : yp);
        int rx = kj == 0 ? xm : (kj == 1 ? x : xp);
        nidx[s] = ry * IW + rx;
    }

    float av0 = 0.f, av1 = 0.f, av2 = 0.f;
    #pragma unroll
    for (int c = 0; c < CI; ++c) {
        const float* p = img + c * HW;
        float center = p[y * IW + x];
        float n0 = p[nidx[0]], n1 = p[nidx[1]], n2 = p[nidx[2]];
        float s1 = n0 + n1 + n2;
        float s2 = n0 * n0 + n1 * n1 + n2 * n2;
        #pragma unroll
        for (int off = 1; off < 16; off <<= 1) {
            s1 += __shfl_xor(s1, off, 16);
            s2 += __shfl_xor(s2, off, 16);
        }
        float mean = s1 * (1.f / (float)K);
        float ss = s2 - (float)K * mean * mean;
        float inv = 1.f / (sqrtf(fmaxf(ss, 0.f) * (1.f / (float)(K - 1))) + EPS);
        float t0 = fabsf(n0 - center) * inv; av0 += t0 * t0;
        float t1 = fabsf(n1 - center) * inv; av1 += t1 * t1;
        float t2 = fabsf(n2 - center) * inv; av2 += t2 * t2;
    }
    const float sc = -(1.f / (float)CI) / (0.3f * 0.3f);
    av0 *= sc; av1 *= sc; av2 *= sc;
    float m1 = fmaxf(av0, fmaxf(av1, av2));
    #pragma unroll
    for (int off = 1; off < 16; off <<= 1) m1 = fmaxf(m1, __shfl_xor(m1, off, 16));
    float e0 = expf(av0 - m1), e1 = expf(av1 - m1), e2 = expf(av2 - m1);
    float es = e0 + e1 + e2;
    #pragma unroll
    for (int off = 1; off < 16; off <<= 1) es += __shfl_xor(es, off, 16);
    float r1 = 1.f / es;

    float fy = (float)y * ((float)(H2 - 1) / (float)(IH - 1));
    float fx = (float)x * ((float)(W2 - 1) / (float)(IW - 1));
    int y0 = (int)floorf(fy); int y1 = min(y0 + 1, H2 - 1); float wy = fy - (float)y0;
    int x0 = (int)floorf(fx); int x1 = min(x0 + 1, W2 - 1); float wx = fx - (float)x0;
    const float* q00 = aff2 + (size_t)(y0 * W2 + x0) * K;
    const float* q01 = aff2 + (size_t)(y0 * W2 + x1) * K;
    const float* q10 = aff2 + (size_t)(y1 * W2 + x0) * K;
    const float* q11 = aff2 + (size_t)(y1 * W2 + x1) * K;
    float w00 = (1.f - wy) * (1.f - wx), w01 = (1.f - wy) * wx;
    float w10 = wy * (1.f - wx), w11 = wy * wx;
    const float sc2 = -(1.f / (float)CI);
    float b0 = (q00[kk[0]] * w00 + q01[kk[0]] * w01 + q10[kk[0]] * w10 + q11[kk[0]] * w11) * sc2;
    float b1 = (q00[kk[1]] * w00 + q01[kk[1]] * w01 + q10[kk[1]] * w10 + q11[kk[1]] * w11) * sc2;
    float b2 = (q00[kk[2]] * w00 + q01[kk[2]] * w01 + q10[kk[2]] * w10 + q11[kk[2]] * w11) * sc2;
    float m2 = fmaxf(b0, fmaxf(b1, b2));
    #pragma unroll
    for (int off = 1; off < 16; off <<= 1) m2 = fmaxf(m2, __shfl_xor(m2, off, 16));
    float f0 = expf(b0 - m2), f1 = expf(b1 - m2), f2 = expf(b2 - m2);
    float fs = f0 + f1 + f2;
    #pragma unroll
    for (int off = 1; off < 16; off <<= 1) fs += __shfl_xor(fs, off, 16);
    float r2 = 1.f / fs;

    __half* o = afft + (size_t)t * K;
    o[kk[0]] = __float2half(e0 * r1 + f0 * r2 + pos.v[kk[0]]);
    o[kk[1]] = __float2half(e1 * r1 + f1 * r2 + pos.v[kk[1]]);
    o[kk[2]] = __float2half(e2 * r1 + f2 * r2 + pos.v[kk[2]]);
}

// ---------------- one propagation iteration ---------------------------------
// R12 structure; mask state now FP16: stage 13 rows x 224 halfs = 364 16B
// slots via global_load_lds (1.4 issues/thread, half the L2 bytes), LDS
// 5.8 KB. Compute converts on read (v_cvt_f32_f16 full-rate). LAST writes
// fp32 to d_out; else fp16 to the ping-pong buffer.
template<bool LAST>
__global__ __launch_bounds__(256) void k_prop(const __half* __restrict__ min_,
                                              const __half* __restrict__ afft,
                                              void* __restrict__ mout) {
    __shared__ __half L[13 * 224];   // 5824 B = 364 x 16B slots
    int tid = threadIdx.x;
    int bid = blockIdx.x;
    int sw = (bid & 7) * 588 + (bid >> 3);   // 4704 = 8 * 588, bijective
    int y = sw / 21;
    int c = sw - y * 21;

    // hoist affinity-weight loads (latency hides under staging)
    int x = min(tid, IW - 1);
    int t = y * IW + x;
    uint4 w[6];
    {
        const uint4* aw = (const uint4*)(afft + (size_t)t * K);  // 96 B
        #pragma unroll
        for (int i = 0; i < 6; ++i) w[i] = aw[i];
    }

    // stage 13 rows x 224 halfs: 364 16B slots, direct global->LDS
    const int ROW_DY[13] = {-24, -12, -8, -4, -2, -1, 0, 1, 2, 4, 8, 12, 24};
    const __half* mc = min_ + (size_t)c * HW;
    {
        int i = tid;                       // slots 0..255
        int r = i / 28, q = i - r * 28;
        int gy = min(max(y + ROW_DY[r], 0), IH - 1);
        gload_lds16(mc + gy * IW + q * 8, L + i * 8);
    }
    if (tid < 108) {
        int i = tid + 256;                 // slots 256..363
        int r = i / 28, q = i - r * 28;
        int gy = min(max(y + ROW_DY[r], 0), IH - 1);
        gload_lds16(mc + gy * IW + q * 8, L + i * 8);
    }
    __syncthreads();

    if (tid >= IW) return;

    const int DILS[ND] = {1, 2, 4, 8, 12, 24};
    const int RMI[ND] = {5, 4, 3, 2, 1, 0};
    const int RPI[ND] = {7, 8, 9, 10, 11, 12};
    const __half* Lc = L + 6 * 224;

    float acc = 0.f;
    #pragma unroll
    for (int di = 0; di < ND; ++di) {
        int d = DILS[di];
        int cm = max(x - d, 0);
        int cp = min(x + d, IW - 1);
        const __half* Lm = L + RMI[di] * 224;
        const __half* Lp = L + RPI[di] * 224;
        const __half2* hp = (const __half2*)&w[di];
        float2 f01 = __half22float2(hp[0]);
        float2 f23 = __half22float2(hp[1]);
        float2 f45 = __half22float2(hp[2]);
        float2 f67 = __half22float2(hp[3]);
        acc += __half2float(Lm[cm]) * f01.x;
        acc += __half2float(Lm[x])  * f01.y;
        acc += __half2float(Lm[cp]) * f23.x;
        acc += __half2float(Lc[cm]) * f23.y;
        acc += __half2float(Lc[cp]) * f45.x;
        acc += __half2float(Lp[cm]) * f45.y;
        acc += __half2float(Lp[x])  * f67.x;
        acc += __half2float(Lp[cp]) * f67.y;
    }
    if (LAST) {
        ((float*)mout)[(size_t)c * HW + t] = acc;
    } else {
        ((__half*)mout)[(size_t)c * HW + t] = __float2half(acc);
    }
}

extern "C" void kernel_launch(void* const* d_in, const int* in_sizes, int n_in,
                              void* d_out, int out_size, void* d_ws, size_t ws_size,
                              hipStream_t stream) {
    const float* imgs  = (const float*)d_in[0];
    const float* masks = (const float*)d_in[1];
    float* out = (float*)d_out;

    float* ws = (float*)d_ws;
    float* imgs2 = ws;                       // CI*HW2 = 13467 -> pad to 16384
    float* aff2  = imgs2 + 16384;            // HW2*K  = 215472 (layout [HW2][K])
    __half* afft = (__half*)(aff2 + K * HW2);   // HW*K halfs = 4.8 MB
    __half* mA   = afft + (size_t)K * HW;       // CM*HW halfs = 2.1 MB
    __half* mB   = mA + (size_t)CM * HW;

    // host-side positional softmax (input-independent, same every call)
    PosArr pos;
    {
        double pv[K];
        const int dil[ND] = {1, 2, 4, 8, 12, 24};
        const double s2 = sqrt(2.0);
        for (int di = 0; di < ND; ++di)
            for (int o = 0; o < 8; ++o) {
                double base = (o == 0 || o == 2 || o == 5 || o == 7) ? s2 : 1.0;
                pv[di * 8 + o] = base * (double)dil[di];
            }
        double sum = 0.0; for (int k = 0; k < K; ++k) sum += pv[k];
        double mean = sum / K;
        double ssd = 0.0; for (int k = 0; k < K; ++k) { double d0 = pv[k] - mean; ssd += d0 * d0; }
        double stdv = sqrt(ssd / (K - 1));
        double pa[K];
        double mx = -1e300;
        for (int k = 0; k < K; ++k) {
            double u = pv[k] / (stdv + 1e-8) / 0.3;
            pa[k] = -u * u;
            if (pa[k] > mx) mx = pa[k];
        }
        double es = 0.0, ev[K];
        for (int k = 0; k < K; ++k) { ev[k] = exp(pa[k] - mx); es += ev[k]; }
        for (int k = 0; k < K; ++k) pos.v[k] = (float)(ev[k] / es);
    }

    dim3 blk(256);
    k_prep<<<(CM * HW + 255) / 256, blk, 0, stream>>>(imgs, imgs2, masks, mA);
    k_aff2<<<(HW2 * 64 + 255) / 256, blk, 0, stream>>>(imgs2, aff2);
    k_aff_total<<<(HW * 16 + 255) / 256, blk, 0, stream>>>(imgs, aff2, afft, pos);

    __half* bufs[2] = {mA, mB};
    const __half* cur = mA;
    for (int i = 0; i < 9; ++i) {
        __half* o = bufs[(i + 1) & 1];
        k_prop<false><<<4704, blk, 0, stream>>>(cur, afft, (void*)o);
        cur = o;
    }
    k_prop<true><<<4704, blk, 0, stream>>>(cur, afft, (void*)out);
}